// Round 7
// baseline (186.808 us; speedup 1.0000x reference)
//
#include <hip/hip_runtime.h>
#include <hip/hip_bf16.h>
#include <cmath>

typedef unsigned short u16;
typedef __bf16 bf16x8 __attribute__((ext_vector_type(8)));
typedef float  f32x4  __attribute__((ext_vector_type(4)));
typedef float  f4     __attribute__((ext_vector_type(4)));
typedef u16    us4    __attribute__((ext_vector_type(4)));

#define DEVFN __device__ __forceinline__

static constexpr int Bq = 2, Nq = 2048, Eq = 1024;
static constexpr int Mq = Bq * Nq;        // 4096 tokens
static constexpr int CHK = 64;            // attention chunk
static constexpr int NC  = Nq / CHK;      // 32 chunks
static constexpr int BH  = Bq * 16;       // 32

DEVFN u16 f2b(float f) {                  // f32 -> bf16 (RNE), finite inputs
    union { float f; unsigned int u; } x; x.f = f;
    unsigned int r = x.u + 0x7fffu + ((x.u >> 16) & 1u);
    return (u16)(r >> 16);
}
DEVFN float b2f(u16 v) {
    union { unsigned int u; float f; } x; x.u = ((unsigned int)v) << 16; return x.f;
}

// ---------------- all f32 -> bf16 converts in ONE launch ----------------
__global__ __launch_bounds__(256)
void cvt_all_kernel(const float* __restrict__ x,
                    const float* __restrict__ w0, const float* __restrict__ w1,
                    const float* __restrict__ w2, const float* __restrict__ w3,
                    u16* __restrict__ Xb, u16* __restrict__ Wb)
{
    const int blk = blockIdx.x;
    const float* s; u16* d; int i;
    if (blk < 4096) {
        i = blk * 256 + threadIdx.x;  s = x;  d = Xb;
    } else {
        const int wsel = (blk - 4096) >> 10;
        i = ((blk - 4096) & 1023) * 256 + threadIdx.x;
        s = (wsel == 0) ? w0 : (wsel == 1) ? w1 : (wsel == 2) ? w2 : w3;
        d = Wb + (size_t)wsel * (Eq * Eq);
    }
    f4 v = *reinterpret_cast<const f4*>(&s[(size_t)i * 4]);
    us4 p; p[0] = f2b(v[0]); p[1] = f2b(v[1]); p[2] = f2b(v[2]); p[3] = f2b(v[3]);
    *reinterpret_cast<us4*>(&d[(size_t)i * 4]) = p;
}

// ======== direct-to-register GEMM: NO LDS, NO barriers, per-wave pipeline ========
// out[m][n] = act(sum_k X[m][k]*W[n][k] + bias[n])
// Each wave owns a tile (MODE0: 64x64, MODE1: 32x64) and streams A/B fragments
// straight from global (frag = 16 rows x 64B lines, fully line-utilized) with a
// 2-deep register double buffer. Compiler inserts per-use vmcnt; no sync stalls.
// MODE 0: fused QKV, block 128x128 (4 waves 2x2), N=3072.
// MODE 1: O-projection, block 64x128 (4 waves 2x2 of 32x64), N=1024, f32 out.
template<int MODE>
__global__ __launch_bounds__(256)
void gemm_direct(const u16* __restrict__ X, const u16* __restrict__ W,
                 const float* __restrict__ b0, const float* __restrict__ b1,
                 const float* __restrict__ b2,
                 u16* __restrict__ Qb, u16* __restrict__ Kb, u16* __restrict__ KbT,
                 u16* __restrict__ VbT, float* __restrict__ outF)
{
    constexpr int MI = (MODE == 0) ? 4 : 2;    // M-frags per wave
    const int tid = threadIdx.x, wid = tid >> 6, lane = tid & 63;
    const int fr = lane & 15, fq = lane >> 4;
    const int bid = blockIdx.x;
    // XCD-bijective swizzle (grid 768 / 512, both %8==0)
    const int fid = (MODE == 0) ? ((bid & 7) * 96 + (bid >> 3))
                                : ((bid & 7) * 64 + (bid >> 3));
    const int bx  = (MODE == 0) ? (fid % 24) : (fid & 7);
    const int by  = (MODE == 0) ? (fid / 24) : (fid >> 3);
    const int m0  = (MODE == 0) ? (by * 128 + (wid >> 1) * 64)
                                : (by * 64  + (wid >> 1) * 32);
    const int n0  = bx * 128 + (wid & 1) * 64;

    // fragment base pointers (per-lane): row = tile_row + fr, col byte = fq*16
    const u16* pa[MI];
    const u16* pb[4];
#pragma unroll
    for (int mi = 0; mi < MI; ++mi)
        pa[mi] = X + (size_t)(m0 + mi * 16 + fr) * 1024 + fq * 8;
#pragma unroll
    for (int ni = 0; ni < 4; ++ni)
        pb[ni] = W + (size_t)(n0 + ni * 16 + fr) * 1024 + fq * 8;

#define LD(as, bs, t) do {                                                   \
        _Pragma("unroll")                                                    \
        for (int mi = 0; mi < MI; ++mi)                                      \
            as[mi] = *reinterpret_cast<const bf16x8*>(pa[mi] + (t) * 32);    \
        _Pragma("unroll")                                                    \
        for (int ni = 0; ni < 4; ++ni)                                       \
            bs[ni] = *reinterpret_cast<const bf16x8*>(pb[ni] + (t) * 32);    \
    } while (0)
#define FM(as, bs) do {                                                      \
        _Pragma("unroll")                                                    \
        for (int mi = 0; mi < MI; ++mi)                                      \
            _Pragma("unroll")                                                \
            for (int ni = 0; ni < 4; ++ni)                                   \
                acc[mi][ni] = __builtin_amdgcn_mfma_f32_16x16x32_bf16(       \
                    as[mi], bs[ni], acc[mi][ni], 0, 0, 0);                   \
    } while (0)

    f32x4 acc[MI][4] = {};
    bf16x8 aX[MI], bX[4], aY[MI], bY[4];
    LD(aX, bX, 0);
#pragma unroll 4
    for (int t = 0; t < 32; t += 2) {
        LD(aY, bY, t + 1);                      // prefetch next tile's frags
        FM(aX, bX);
        if (t + 2 < 32) LD(aX, bX, t + 2);
        FM(aY, bY);
        if ((t & 7) == 6) __builtin_amdgcn_s_barrier();   // cheap re-sync for L1 reuse
    }
#undef LD
#undef FM

    if (MODE == 0) {
        const int seg = n0 >> 10;                          // 0=q 1=k 2=v
        const float* bp = (seg == 0) ? b0 : (seg == 1) ? b1 : b2;
#pragma unroll
        for (int mi = 0; mi < MI; ++mi)
#pragma unroll
            for (int ni = 0; ni < 4; ++ni) {
                const int nl    = (n0 & 1023) + ni * 16 + fr;
                const int mbase = m0 + mi * 16 + fq * 4;
                const float bn  = bp[nl];
                float vr[4];
#pragma unroll
                for (int r = 0; r < 4; ++r) {
                    float v = acc[mi][ni][r] + bn;
                    if (seg < 2) v = (v > 0.f) ? (v + 1.f) : __expf(v);  // elu+1
                    vr[r] = v;
                }
                if (seg == 0) {
#pragma unroll
                    for (int r = 0; r < 4; ++r)
                        Qb[(size_t)(mbase + r) * 1024 + nl] = f2b(vr[r]);
                } else {
                    us4 pk;
#pragma unroll
                    for (int r = 0; r < 4; ++r) pk[r] = f2b(vr[r]);
                    const int bb = mbase >> 11, nt = mbase & 2047;
                    const int hh = nl >> 6,     dd = nl & 63;
                    u16* T = (seg == 1) ? KbT : VbT;
                    *reinterpret_cast<us4*>(
                        &T[((size_t)(bb * 16 + hh) * 64 + dd) * 2048 + nt]) = pk;
                    if (seg == 1) {
#pragma unroll
                        for (int r = 0; r < 4; ++r)
                            Kb[(size_t)(mbase + r) * 1024 + nl] = f2b(vr[r]);
                    }
                }
            }
    } else {
#pragma unroll
        for (int mi = 0; mi < MI; ++mi)
#pragma unroll
            for (int ni = 0; ni < 4; ++ni) {
                const int n     = n0 + ni * 16 + fr;
                const int mbase = m0 + mi * 16 + fq * 4;
                const float bn  = b0[n];
#pragma unroll
                for (int r = 0; r < 4; ++r)
                    outF[(size_t)(mbase + r) * 1024 + n] = acc[mi][ni][r] + bn;
            }
    }
}

// ---------------- per-chunk KV^T = v^T @ k: KVT[de][dk], bf16 out ----------------
__global__ __launch_bounds__(64)
void chunk_kv_kernel(const u16* __restrict__ KbT, const u16* __restrict__ VbT,
                     u16* __restrict__ KVT)
{
    const int blk = blockIdx.x;          // bh*NC + c
    const int bh = blk >> 5, c = blk & 31;
    const int lane = threadIdx.x;
    const int fr = lane & 15, fq = lane >> 4, fk = fq * 8;
    const u16* kt = KbT + (size_t)bh * 64 * 2048;
    const u16* vt = VbT + (size_t)bh * 64 * 2048;

    bf16x8 a[4][2], b[4][2];             // a = V rows (de), b = K rows (dk)
#pragma unroll
    for (int mi = 0; mi < 4; ++mi)
#pragma unroll
        for (int kh = 0; kh < 2; ++kh)
            a[mi][kh] = *reinterpret_cast<const bf16x8*>(
                &vt[(size_t)(mi * 16 + fr) * 2048 + c * 64 + kh * 32 + fk]);
#pragma unroll
    for (int ni = 0; ni < 4; ++ni)
#pragma unroll
        for (int kh = 0; kh < 2; ++kh)
            b[ni][kh] = *reinterpret_cast<const bf16x8*>(
                &kt[(size_t)(ni * 16 + fr) * 2048 + c * 64 + kh * 32 + fk]);

    f32x4 acc[4][4] = {};
    __builtin_amdgcn_s_setprio(1);
#pragma unroll
    for (int mi = 0; mi < 4; ++mi)
#pragma unroll
        for (int ni = 0; ni < 4; ++ni)
#pragma unroll
            for (int kh = 0; kh < 2; ++kh)
                acc[mi][ni] = __builtin_amdgcn_mfma_f32_16x16x32_bf16(
                    a[mi][kh], b[ni][kh], acc[mi][ni], 0, 0, 0);
    __builtin_amdgcn_s_setprio(0);

    u16* out = KVT + (size_t)blk * 4096;   // [de][dk] bf16
#pragma unroll
    for (int mi = 0; mi < 4; ++mi)
#pragma unroll
        for (int ni = 0; ni < 4; ++ni)
#pragma unroll
            for (int r = 0; r < 4; ++r)
                out[(mi * 16 + fq * 4 + r) * 64 + ni * 16 + fr] = f2b(acc[mi][ni][r]);
}

// ---------------- elementwise exclusive scan over chunks (bf16 in/out) ----------------
__global__ __launch_bounds__(256)
void scan_kernel(const u16* __restrict__ KVT, u16* __restrict__ STb)
{
    const int bh = blockIdx.x >> 4, sl = blockIdx.x & 15;
    const int el = sl * 256 + threadIdx.x;              // element of [de][dk]
    const u16* src = KVT + (size_t)bh * NC * 4096 + el;
    u16*      dst  = STb + (size_t)bh * NC * 4096 + el;
    float run = 0.f;
#pragma unroll 4
    for (int c = 0; c < NC; ++c) {
        dst[(size_t)c * 4096] = f2b(run);               // exclusive prefix
        run += b2f(src[(size_t)c * 4096]);
    }
}

// ---------------- per-chunk attention output ----------------
__global__ __launch_bounds__(64)
void attn_kernel(const u16* __restrict__ Qb, const u16* __restrict__ Kb,
                 const u16* __restrict__ VbT, const u16* __restrict__ STb,
                 u16* __restrict__ Ob)
{
    __shared__ u16 P[64 * 72];   // stride 72 u16 = 144B: 16B-aligned, 2-way banks
    const int blk = blockIdx.x;
    const int bh = blk >> 5, c = blk & 31;
    const int b = bh >> 4, h = bh & 15;
    const int lane = threadIdx.x;
    const int fr = lane & 15, fq = lane >> 4, fk = fq * 8;
    const int tok0 = b * 2048 + c * 64;

    bf16x8 qa[4][2];
#pragma unroll
    for (int mi = 0; mi < 4; ++mi)
#pragma unroll
        for (int kh = 0; kh < 2; ++kh)
            qa[mi][kh] = *reinterpret_cast<const bf16x8*>(
                &Qb[(size_t)(tok0 + mi * 16 + fr) * 1024 + h * 64 + kh * 32 + fk]);

    // P = causal-mask(q @ k^T) -> LDS bf16
    {
        bf16x8 kb[4][2];
#pragma unroll
        for (int si = 0; si < 4; ++si)
#pragma unroll
            for (int kh = 0; kh < 2; ++kh)
                kb[si][kh] = *reinterpret_cast<const bf16x8*>(
                    &Kb[(size_t)(tok0 + si * 16 + fr) * 1024 + h * 64 + kh * 32 + fk]);
        f32x4 p[4][4] = {};
        __builtin_amdgcn_s_setprio(1);
#pragma unroll
        for (int mi = 0; mi < 4; ++mi)
#pragma unroll
            for (int si = 0; si < 4; ++si)
#pragma unroll
                for (int kh = 0; kh < 2; ++kh)
                    p[mi][si] = __builtin_amdgcn_mfma_f32_16x16x32_bf16(
                        qa[mi][kh], kb[si][kh], p[mi][si], 0, 0, 0);
        __builtin_amdgcn_s_setprio(0);
#pragma unroll
        for (int mi = 0; mi < 4; ++mi)
#pragma unroll
            for (int si = 0; si < 4; ++si)
#pragma unroll
                for (int r = 0; r < 4; ++r) {
                    int t = mi * 16 + fq * 4 + r;
                    int s = si * 16 + fr;
                    float v = (s <= t) ? p[mi][si][r] : 0.0f;
                    P[t * 72 + s] = f2b(v);
                }
    }
    __syncthreads();

    f32x4 acc[4][4] = {};
    // acc = q @ ST   (STb[de][dk], dk-contiguous)
    {
        const u16* st = STb + (size_t)blk * 4096;
        bf16x8 sb[4][2];
#pragma unroll
        for (int ni = 0; ni < 4; ++ni)
#pragma unroll
            for (int kh = 0; kh < 2; ++kh)
                sb[ni][kh] = *reinterpret_cast<const bf16x8*>(
                    &st[(ni * 16 + fr) * 64 + kh * 32 + fk]);
        __builtin_amdgcn_s_setprio(1);
#pragma unroll
        for (int mi = 0; mi < 4; ++mi)
#pragma unroll
            for (int ni = 0; ni < 4; ++ni)
#pragma unroll
                for (int kh = 0; kh < 2; ++kh)
                    acc[mi][ni] = __builtin_amdgcn_mfma_f32_16x16x32_bf16(
                        qa[mi][kh], sb[ni][kh], acc[mi][ni], 0, 0, 0);
        __builtin_amdgcn_s_setprio(0);
    }
    // acc += P @ v
    {
        const u16* vt = VbT + (size_t)bh * 64 * 2048;
#pragma unroll
        for (int sh = 0; sh < 2; ++sh) {
            bf16x8 pa[4], vb[4];
#pragma unroll
            for (int mi = 0; mi < 4; ++mi)
                pa[mi] = *reinterpret_cast<const bf16x8*>(
                    &P[(mi * 16 + fr) * 72 + sh * 32 + fk]);
#pragma unroll
            for (int ni = 0; ni < 4; ++ni)
                vb[ni] = *reinterpret_cast<const bf16x8*>(
                    &vt[(size_t)(ni * 16 + fr) * 2048 + c * 64 + sh * 32 + fk]);
            __builtin_amdgcn_s_setprio(1);
#pragma unroll
            for (int mi = 0; mi < 4; ++mi)
#pragma unroll
                for (int ni = 0; ni < 4; ++ni)
                    acc[mi][ni] = __builtin_amdgcn_mfma_f32_16x16x32_bf16(
                        pa[mi], vb[ni], acc[mi][ni], 0, 0, 0);
            __builtin_amdgcn_s_setprio(0);
        }
    }
    // write token-major bf16 O
#pragma unroll
    for (int mi = 0; mi < 4; ++mi)
#pragma unroll
        for (int ni = 0; ni < 4; ++ni)
#pragma unroll
            for (int r = 0; r < 4; ++r) {
                int t = tok0 + mi * 16 + fq * 4 + r;
                int n = h * 64 + ni * 16 + fr;
                Ob[(size_t)t * 1024 + n] = f2b(acc[mi][ni][r]);
            }
}

extern "C" void kernel_launch(void* const* d_in, const int* in_sizes, int n_in,
                              void* d_out, int out_size, void* d_ws, size_t ws_size,
                              hipStream_t stream)
{
    (void)in_sizes; (void)n_in; (void)out_size; (void)ws_size;
    const float* x  = (const float*)d_in[0];
    const float* Wq = (const float*)d_in[1];
    const float* bq = (const float*)d_in[2];
    const float* Wk = (const float*)d_in[3];
    const float* bk = (const float*)d_in[4];
    const float* Wv = (const float*)d_in[5];
    const float* bv = (const float*)d_in[6];
    const float* Wo = (const float*)d_in[7];
    const float* bo = (const float*)d_in[8];
    float* out = (float*)d_out;

    char* ws = (char*)d_ws;
    constexpr size_t SZ_ME = (size_t)Mq * Eq * 2;        // 8 MB
    u16*   Qb  = (u16*)  (ws + 0 * SZ_ME);
    u16*   Kb  = (u16*)  (ws + 1 * SZ_ME);
    u16*   KbT = (u16*)  (ws + 2 * SZ_ME);
    u16*   VbT = (u16*)  (ws + 3 * SZ_ME);
    u16*   Ob  = (u16*)  (ws + 4 * SZ_ME);
    u16*   KVT = (u16*)  (ws + 5 * SZ_ME);               // 8 MB bf16
    u16*   STb = (u16*)  (ws + 6 * SZ_ME);
    u16*   Xb  = (u16*)  (ws + 7 * SZ_ME);
    u16*   Wb0 = (u16*)  (ws + 8 * SZ_ME);               // [Wq|Wk|Wv|Wo] bf16
    u16* Wqkvb = Wb0;
    u16* Wob   = Wb0 + (size_t)3 * Eq * Eq;

    // 1) all bf16 conversions, one launch
    cvt_all_kernel<<<dim3(8192), dim3(256), 0, stream>>>(x, Wq, Wk, Wv, Wo, Xb, Wb0);

    // 2) fused QKV projection (M=4096, N=3072): direct-to-reg, 768 blocks
    gemm_direct<0><<<dim3(768), dim3(256), 0, stream>>>(
        Xb, Wqkvb, bq, bk, bv, Qb, Kb, KbT, VbT, nullptr);

    // 3) attention
    chunk_kv_kernel<<<dim3(BH * NC), dim3(64), 0, stream>>>(KbT, VbT, KVT);
    scan_kernel<<<dim3(BH * 16), dim3(256), 0, stream>>>(KVT, STb);
    attn_kernel<<<dim3(BH * NC), dim3(64), 0, stream>>>(Qb, Kb, VbT, STb, Ob);

    // 4) output projection (M=4096, N=1024): direct-to-reg, 512 blocks
    gemm_direct<1><<<dim3(512), dim3(256), 0, stream>>>(
        Ob, Wob, bo, nullptr, nullptr, nullptr, nullptr, nullptr, nullptr, out);
}

// Round 8
// 95.364 us; speedup vs baseline: 1.9589x; 1.9589x over previous
//
#include <hip/hip_runtime.h>
#include <hip/hip_bf16.h>
#include <cmath>

typedef unsigned short u16;
typedef __bf16 bf16x8 __attribute__((ext_vector_type(8)));
typedef float  f32x4  __attribute__((ext_vector_type(4)));
typedef float  f4     __attribute__((ext_vector_type(4)));
typedef u16    us4    __attribute__((ext_vector_type(4)));

#define DEVFN __device__ __forceinline__

static constexpr int Bq = 2, Nq = 2048, Eq = 1024;
static constexpr int Mq = Bq * Nq;        // 4096 tokens
static constexpr int CHK = 64;            // attention chunk
static constexpr int NC  = Nq / CHK;      // 32 chunks
static constexpr int BH  = Bq * 16;       // 32

DEVFN u16 f2b(float f) {                  // f32 -> bf16 (RNE), finite inputs
    union { float f; unsigned int u; } x; x.f = f;
    unsigned int r = x.u + 0x7fffu + ((x.u >> 16) & 1u);
    return (u16)(r >> 16);
}
DEVFN float b2f(u16 v) {
    union { unsigned int u; float f; } x; x.u = ((unsigned int)v) << 16; return x.f;
}

DEVFN void gl_lds16(const u16* g, u16* l) {  // async 16B global->LDS (dest: wave base + lane*16)
    __builtin_amdgcn_global_load_lds(
        (const __attribute__((address_space(1))) unsigned int*)(g),
        (__attribute__((address_space(3))) unsigned int*)(l),
        16, 0, 0);
}

// ---------------- all f32 -> bf16 converts in ONE launch ----------------
__global__ __launch_bounds__(256)
void cvt_all_kernel(const float* __restrict__ x,
                    const float* __restrict__ w0, const float* __restrict__ w1,
                    const float* __restrict__ w2, const float* __restrict__ w3,
                    u16* __restrict__ Xb, u16* __restrict__ Wb)
{
    const int blk = blockIdx.x;
    const float* s; u16* d; int i;
    if (blk < 4096) {
        i = blk * 256 + threadIdx.x;  s = x;  d = Xb;
    } else {
        const int wsel = (blk - 4096) >> 10;
        i = ((blk - 4096) & 1023) * 256 + threadIdx.x;
        s = (wsel == 0) ? w0 : (wsel == 1) ? w1 : (wsel == 2) ? w2 : w3;
        d = Wb + (size_t)wsel * (Eq * Eq);
    }
    f4 v = *reinterpret_cast<const f4*>(&s[(size_t)i * 4]);
    us4 p; p[0] = f2b(v[0]); p[1] = f2b(v[1]); p[2] = f2b(v[2]); p[3] = f2b(v[3]);
    *reinterpret_cast<us4*>(&d[(size_t)i * 4]) = p;
}

// ======== QKV: 256x256 tile, 8 waves, BK=32, ring-3 LDS, 2 fine phases/K-tile ========
// m201-geometry port: per phase {ds_read subtile + 2 gl_lds stage + barrier +
// setprio(1) 16 MFMA setprio(0) + barrier}; counted vmcnt(4) once per K-tile.
// Ring-3 at K-tile granularity: compute buf[t%3], stage t+2 into buf[(t+2)%3].
__global__ __launch_bounds__(512, 2)
void qkv8_kernel(const u16* __restrict__ X, const u16* __restrict__ W,
                 const float* __restrict__ b0, const float* __restrict__ b1,
                 const float* __restrict__ b2,
                 u16* __restrict__ Qb, u16* __restrict__ Kb, u16* __restrict__ KbT,
                 u16* __restrict__ VbT)
{
    __shared__ u16 lds[3 * 16384];            // 96KB: 3 bufs x (A 16KB | B 16KB)
    const int tid = threadIdx.x, wid = tid >> 6, lane = tid & 63;
    const int wm = wid >> 2, wn = wid & 3;    // wave tile: rows wm*128..+127, cols wn*64..+63
    const int fr = lane & 15, fq = lane >> 4;

    const int bid = blockIdx.x;               // grid 192 = 8 * 24 (XCD-bijective)
    const int fid = (bid & 7) * 24 + (bid >> 3);
    const int bx = fid % 12, by = fid / 12;
    const int m0 = by * 256, n0 = bx * 256;

    // staging: one round = 512 thr x 16B = 128 rows; row = tid>>2, slot = tid&3
    // source slot XOR-swizzled with (row>>1)&3 (involution; proven 0-conflict in R6)
    const int ra = tid >> 2;
    const int sc = ((tid & 3) ^ ((tid >> 3) & 3)) * 8;
    const u16* gA = X + (size_t)(m0 + ra) * 1024 + sc;
    const u16* gB = W + (size_t)(n0 + ra) * 1024 + sc;
    const int dw = wid * 512;                 // wave-uniform dest piece (1KB/wave/round)

    // fragment reads: same involution on read side
    const int fsw = (fq ^ ((fr >> 1) & 3)) << 3;
    int aoff[2][4], boff[4];
#pragma unroll
    for (int h = 0; h < 2; ++h)
#pragma unroll
        for (int j = 0; j < 4; ++j)
            aoff[h][j] = (wm * 128 + h * 64 + j * 16 + fr) * 32 + fsw;
#pragma unroll
    for (int j = 0; j < 4; ++j)
        boff[j] = 8192 + (wn * 64 + j * 16 + fr) * 32 + fsw;

#define STA(kt, bs) do { u16* _b = lds + (bs) * 16384 + dw;                      \
        gl_lds16(gA + (kt) * 32,              _b);                               \
        gl_lds16(gA + (kt) * 32 + 128 * 1024, _b + 4096); } while (0)
#define STB(kt, bs) do { u16* _b = lds + (bs) * 16384 + 8192 + dw;               \
        gl_lds16(gB + (kt) * 32,              _b);                               \
        gl_lds16(gB + (kt) * 32 + 128 * 1024, _b + 4096); } while (0)

    // prologue: tiles 0,1 staged; tile0 landed (tile1's 4 loads stay in flight)
    STA(0, 0); STB(0, 0);
    STA(1, 1); STB(1, 1);
    asm volatile("s_waitcnt vmcnt(4)" ::: "memory");
    __builtin_amdgcn_sched_barrier(0);
    __builtin_amdgcn_s_barrier();

    f32x4 acc[8][4] = {};
    int cb = 0, sb = 2;

    for (int t = 0; t < 32; ++t) {
        const u16* buf = lds + cb * 16384;
        bf16x8 a[4], b[4];
        // ---------- phase 0: rows wm*128 .. +63 ----------
#pragma unroll
        for (int j = 0; j < 4; ++j)
            a[j] = *reinterpret_cast<const bf16x8*>(&buf[aoff[0][j]]);
#pragma unroll
        for (int j = 0; j < 4; ++j)
            b[j] = *reinterpret_cast<const bf16x8*>(&buf[boff[j]]);
        if (t + 2 < 32) STA(t + 2, sb);
        __builtin_amdgcn_s_barrier();
        __builtin_amdgcn_s_setprio(1);
#pragma unroll
        for (int j = 0; j < 4; ++j)
#pragma unroll
            for (int n = 0; n < 4; ++n)
                acc[j][n] = __builtin_amdgcn_mfma_f32_16x16x32_bf16(
                    a[j], b[n], acc[j][n], 0, 0, 0);
        __builtin_amdgcn_s_setprio(0);
        __builtin_amdgcn_s_barrier();
        // ---------- phase 1: rows wm*128+64 .. +127 (b reused from regs) ----------
#pragma unroll
        for (int j = 0; j < 4; ++j)
            a[j] = *reinterpret_cast<const bf16x8*>(&buf[aoff[1][j]]);
        if (t + 2 < 32) STB(t + 2, sb);
        __builtin_amdgcn_s_barrier();
        __builtin_amdgcn_s_setprio(1);
#pragma unroll
        for (int j = 0; j < 4; ++j)
#pragma unroll
            for (int n = 0; n < 4; ++n)
                acc[4 + j][n] = __builtin_amdgcn_mfma_f32_16x16x32_bf16(
                    a[j], b[n], acc[4 + j][n], 0, 0, 0);
        __builtin_amdgcn_s_setprio(0);
        // K-tile boundary: t+1 landed; t+2's 4 loads stay in flight
        if (t < 30)       asm volatile("s_waitcnt vmcnt(4)" ::: "memory");
        else if (t == 30) asm volatile("s_waitcnt vmcnt(0)" ::: "memory");
        __builtin_amdgcn_sched_barrier(0);
        __builtin_amdgcn_s_barrier();
        cb = (cb == 2) ? 0 : cb + 1;
        sb = (sb == 2) ? 0 : sb + 1;
    }
#undef STA
#undef STB

    // ---------- epilogue ----------
    const int nw  = n0 + wn * 64;             // wave col base (seg-uniform: 64 | 1024)
    const int seg = nw >> 10;                 // 0=q 1=k 2=v
    const float* bp = (seg == 0) ? b0 : (seg == 1) ? b1 : b2;
#pragma unroll
    for (int mg = 0; mg < 8; ++mg)
#pragma unroll
        for (int ni = 0; ni < 4; ++ni) {
            const int nl    = ((nw & 1023) + ni * 16 + fr);
            const int mbase = m0 + wm * 128 + mg * 16 + fq * 4;
            const float bn  = bp[nl];
            float vr[4];
#pragma unroll
            for (int r = 0; r < 4; ++r) {
                float v = acc[mg][ni][r] + bn;
                if (seg < 2) v = (v > 0.f) ? (v + 1.f) : __expf(v);  // elu+1
                vr[r] = v;
            }
            if (seg == 0) {
#pragma unroll
                for (int r = 0; r < 4; ++r)
                    Qb[(size_t)(mbase + r) * 1024 + nl] = f2b(vr[r]);
            } else {
                us4 pk;
#pragma unroll
                for (int r = 0; r < 4; ++r) pk[r] = f2b(vr[r]);
                const int bb = mbase >> 11, nt = mbase & 2047;
                const int hh = nl >> 6,     dd = nl & 63;
                u16* T = (seg == 1) ? KbT : VbT;
                *reinterpret_cast<us4*>(
                    &T[((size_t)(bb * 16 + hh) * 64 + dd) * 2048 + nt]) = pk;
                if (seg == 1) {
#pragma unroll
                    for (int r = 0; r < 4; ++r)
                        Kb[(size_t)(mbase + r) * 1024 + nl] = f2b(vr[r]);
                }
            }
        }
}

// ======== O-proj: 64x128 tile, 4 waves, BK=32, ring-3, dup-free staging ========
__global__ __launch_bounds__(256)
void oproj_kernel(const u16* __restrict__ X, const u16* __restrict__ W,
                  const float* __restrict__ b0, float* __restrict__ outF)
{
    constexpr int BUFU = (64 + 128) * 32;     // 6144 u16 = 12KB per buffer
    __shared__ u16 lds[3 * BUFU];             // 36KB
    const int tid = threadIdx.x, wid = tid >> 6, lane = tid & 63;
    const int wr = (wid >> 1) * 32, wc = (wid & 1) * 64;
    const int fr = lane & 15, fq = lane >> 4;

    const int bid = blockIdx.x;               // grid 512 = 8 * 64
    const int fid = (bid & 7) * 64 + (bid >> 3);
    const int bx = fid & 7, by = fid >> 3;
    const int m0 = by * 64, n0 = bx * 128;

    // staging round = 256 thr x 16B = 64 rows; A: 1 round, B: 2 rounds
    const int ra = tid >> 2;
    const int sc = ((tid & 3) ^ ((tid >> 3) & 3)) * 8;
    const u16* gA = X + (size_t)(m0 + ra) * 1024 + sc;
    const u16* gB = W + (size_t)(n0 + ra) * 1024 + sc;
    const int dw = wid * 512;

    const int fsw = (fq ^ ((fr >> 1) & 3)) << 3;
    int aoff[2], boff[4];
#pragma unroll
    for (int mi = 0; mi < 2; ++mi) aoff[mi] = (wr + mi * 16 + fr) * 32 + fsw;
#pragma unroll
    for (int ni = 0; ni < 4; ++ni) boff[ni] = 2048 + (wc + ni * 16 + fr) * 32 + fsw;

#define STAGE(kt, bs) do { u16* _b = lds + (bs) * BUFU;                          \
        gl_lds16(gA + (kt) * 32,             _b + dw);                           \
        gl_lds16(gB + (kt) * 32,             _b + 2048 + dw);                    \
        gl_lds16(gB + (kt) * 32 + 64 * 1024, _b + 4096 + dw); } while (0)

    STAGE(0, 0);
    STAGE(1, 1);
    asm volatile("s_waitcnt vmcnt(3)" ::: "memory");
    __builtin_amdgcn_sched_barrier(0);
    __builtin_amdgcn_s_barrier();

    f32x4 acc[2][4] = {};
    int cb = 0, sb = 2;

    for (int t = 0; t < 32; ++t) {
        if (t + 2 < 32) STAGE(t + 2, sb);
        const u16* buf = lds + cb * BUFU;
        bf16x8 af[2], bfv[4];
#pragma unroll
        for (int mi = 0; mi < 2; ++mi)
            af[mi] = *reinterpret_cast<const bf16x8*>(&buf[aoff[mi]]);
#pragma unroll
        for (int ni = 0; ni < 4; ++ni)
            bfv[ni] = *reinterpret_cast<const bf16x8*>(&buf[boff[ni]]);
        __builtin_amdgcn_s_setprio(1);
#pragma unroll
        for (int mi = 0; mi < 2; ++mi)
#pragma unroll
            for (int ni = 0; ni < 4; ++ni)
                acc[mi][ni] = __builtin_amdgcn_mfma_f32_16x16x32_bf16(
                    af[mi], bfv[ni], acc[mi][ni], 0, 0, 0);
        __builtin_amdgcn_s_setprio(0);
        if (t < 30)       asm volatile("s_waitcnt vmcnt(3)" ::: "memory");
        else if (t == 30) asm volatile("s_waitcnt vmcnt(0)" ::: "memory");
        __builtin_amdgcn_sched_barrier(0);
        __builtin_amdgcn_s_barrier();
        cb = (cb == 2) ? 0 : cb + 1;
        sb = (sb == 2) ? 0 : sb + 1;
    }
#undef STAGE

#pragma unroll
    for (int mi = 0; mi < 2; ++mi)
#pragma unroll
        for (int ni = 0; ni < 4; ++ni) {
            const int n     = n0 + wc + ni * 16 + fr;
            const int mbase = m0 + wr + mi * 16 + fq * 4;
            const float bn  = b0[n];
#pragma unroll
            for (int r = 0; r < 4; ++r)
                outF[(size_t)(mbase + r) * 1024 + n] = acc[mi][ni][r] + bn;
        }
}

// ---------------- per-chunk KV^T = v^T @ k: KVT[de][dk], bf16 out ----------------
__global__ __launch_bounds__(64)
void chunk_kv_kernel(const u16* __restrict__ KbT, const u16* __restrict__ VbT,
                     u16* __restrict__ KVT)
{
    const int blk = blockIdx.x;          // bh*NC + c
    const int bh = blk >> 5, c = blk & 31;
    const int lane = threadIdx.x;
    const int fr = lane & 15, fq = lane >> 4, fk = fq * 8;
    const u16* kt = KbT + (size_t)bh * 64 * 2048;
    const u16* vt = VbT + (size_t)bh * 64 * 2048;

    bf16x8 a[4][2], b[4][2];             // a = V rows (de), b = K rows (dk)
#pragma unroll
    for (int mi = 0; mi < 4; ++mi)
#pragma unroll
        for (int kh = 0; kh < 2; ++kh)
            a[mi][kh] = *reinterpret_cast<const bf16x8*>(
                &vt[(size_t)(mi * 16 + fr) * 2048 + c * 64 + kh * 32 + fk]);
#pragma unroll
    for (int ni = 0; ni < 4; ++ni)
#pragma unroll
        for (int kh = 0; kh < 2; ++kh)
            b[ni][kh] = *reinterpret_cast<const bf16x8*>(
                &kt[(size_t)(ni * 16 + fr) * 2048 + c * 64 + kh * 32 + fk]);

    f32x4 acc[4][4] = {};
    __builtin_amdgcn_s_setprio(1);
#pragma unroll
    for (int mi = 0; mi < 4; ++mi)
#pragma unroll
        for (int ni = 0; ni < 4; ++ni)
#pragma unroll
            for (int kh = 0; kh < 2; ++kh)
                acc[mi][ni] = __builtin_amdgcn_mfma_f32_16x16x32_bf16(
                    a[mi][kh], b[ni][kh], acc[mi][ni], 0, 0, 0);
    __builtin_amdgcn_s_setprio(0);

    u16* out = KVT + (size_t)blk * 4096;   // [de][dk] bf16
#pragma unroll
    for (int mi = 0; mi < 4; ++mi)
#pragma unroll
        for (int ni = 0; ni < 4; ++ni)
#pragma unroll
            for (int r = 0; r < 4; ++r)
                out[(mi * 16 + fq * 4 + r) * 64 + ni * 16 + fr] = f2b(acc[mi][ni][r]);
}

// ---------------- elementwise exclusive scan over chunks (bf16 in/out) ----------------
__global__ __launch_bounds__(256)
void scan_kernel(const u16* __restrict__ KVT, u16* __restrict__ STb)
{
    const int bh = blockIdx.x >> 4, sl = blockIdx.x & 15;
    const int el = sl * 256 + threadIdx.x;              // element of [de][dk]
    const u16* src = KVT + (size_t)bh * NC * 4096 + el;
    u16*      dst  = STb + (size_t)bh * NC * 4096 + el;
    float run = 0.f;
#pragma unroll 4
    for (int c = 0; c < NC; ++c) {
        dst[(size_t)c * 4096] = f2b(run);               // exclusive prefix
        run += b2f(src[(size_t)c * 4096]);
    }
}

// ---------------- per-chunk attention output ----------------
__global__ __launch_bounds__(64)
void attn_kernel(const u16* __restrict__ Qb, const u16* __restrict__ Kb,
                 const u16* __restrict__ VbT, const u16* __restrict__ STb,
                 u16* __restrict__ Ob)
{
    __shared__ u16 P[64 * 72];   // stride 72 u16 = 144B: 16B-aligned, 2-way banks
    const int blk = blockIdx.x;
    const int bh = blk >> 5, c = blk & 31;
    const int b = bh >> 4, h = bh & 15;
    const int lane = threadIdx.x;
    const int fr = lane & 15, fq = lane >> 4, fk = fq * 8;
    const int tok0 = b * 2048 + c * 64;

    bf16x8 qa[4][2];
#pragma unroll
    for (int mi = 0; mi < 4; ++mi)
#pragma unroll
        for (int kh = 0; kh < 2; ++kh)
            qa[mi][kh] = *reinterpret_cast<const bf16x8*>(
                &Qb[(size_t)(tok0 + mi * 16 + fr) * 1024 + h * 64 + kh * 32 + fk]);

    // P = causal-mask(q @ k^T) -> LDS bf16
    {
        bf16x8 kb[4][2];
#pragma unroll
        for (int si = 0; si < 4; ++si)
#pragma unroll
            for (int kh = 0; kh < 2; ++kh)
                kb[si][kh] = *reinterpret_cast<const bf16x8*>(
                    &Kb[(size_t)(tok0 + si * 16 + fr) * 1024 + h * 64 + kh * 32 + fk]);
        f32x4 p[4][4] = {};
        __builtin_amdgcn_s_setprio(1);
#pragma unroll
        for (int mi = 0; mi < 4; ++mi)
#pragma unroll
            for (int si = 0; si < 4; ++si)
#pragma unroll
                for (int kh = 0; kh < 2; ++kh)
                    p[mi][si] = __builtin_amdgcn_mfma_f32_16x16x32_bf16(
                        qa[mi][kh], kb[si][kh], p[mi][si], 0, 0, 0);
        __builtin_amdgcn_s_setprio(0);
#pragma unroll
        for (int mi = 0; mi < 4; ++mi)
#pragma unroll
            for (int si = 0; si < 4; ++si)
#pragma unroll
                for (int r = 0; r < 4; ++r) {
                    int t = mi * 16 + fq * 4 + r;
                    int s = si * 16 + fr;
                    float v = (s <= t) ? p[mi][si][r] : 0.0f;
                    P[t * 72 + s] = f2b(v);
                }
    }
    __syncthreads();

    f32x4 acc[4][4] = {};
    // acc = q @ ST   (STb[de][dk], dk-contiguous)
    {
        const u16* st = STb + (size_t)blk * 4096;
        bf16x8 sb[4][2];
#pragma unroll
        for (int ni = 0; ni < 4; ++ni)
#pragma unroll
            for (int kh = 0; kh < 2; ++kh)
                sb[ni][kh] = *reinterpret_cast<const bf16x8*>(
                    &st[(ni * 16 + fr) * 64 + kh * 32 + fk]);
        __builtin_amdgcn_s_setprio(1);
#pragma unroll
        for (int mi = 0; mi < 4; ++mi)
#pragma unroll
            for (int ni = 0; ni < 4; ++ni)
#pragma unroll
                for (int kh = 0; kh < 2; ++kh)
                    acc[mi][ni] = __builtin_amdgcn_mfma_f32_16x16x32_bf16(
                        qa[mi][kh], sb[ni][kh], acc[mi][ni], 0, 0, 0);
        __builtin_amdgcn_s_setprio(0);
    }
    // acc += P @ v
    {
        const u16* vt = VbT + (size_t)bh * 64 * 2048;
#pragma unroll
        for (int sh = 0; sh < 2; ++sh) {
            bf16x8 pa[4], vb[4];
#pragma unroll
            for (int mi = 0; mi < 4; ++mi)
                pa[mi] = *reinterpret_cast<const bf16x8*>(
                    &P[(mi * 16 + fr) * 72 + sh * 32 + fk]);
#pragma unroll
            for (int ni = 0; ni < 4; ++ni)
                vb[ni] = *reinterpret_cast<const bf16x8*>(
                    &vt[(size_t)(ni * 16 + fr) * 2048 + c * 64 + sh * 32 + fk]);
            __builtin_amdgcn_s_setprio(1);
#pragma unroll
            for (int mi = 0; mi < 4; ++mi)
#pragma unroll
                for (int ni = 0; ni < 4; ++ni)
                    acc[mi][ni] = __builtin_amdgcn_mfma_f32_16x16x32_bf16(
                        pa[mi], vb[ni], acc[mi][ni], 0, 0, 0);
            __builtin_amdgcn_s_setprio(0);
        }
    }
    // write token-major bf16 O
#pragma unroll
    for (int mi = 0; mi < 4; ++mi)
#pragma unroll
        for (int ni = 0; ni < 4; ++ni)
#pragma unroll
            for (int r = 0; r < 4; ++r) {
                int t = tok0 + mi * 16 + fq * 4 + r;
                int n = h * 64 + ni * 16 + fr;
                Ob[(size_t)t * 1024 + n] = f2b(acc[mi][ni][r]);
            }
}

extern "C" void kernel_launch(void* const* d_in, const int* in_sizes, int n_in,
                              void* d_out, int out_size, void* d_ws, size_t ws_size,
                              hipStream_t stream)
{
    (void)in_sizes; (void)n_in; (void)out_size; (void)ws_size;
    const float* x  = (const float*)d_in[0];
    const float* Wq = (const float*)d_in[1];
    const float* bq = (const float*)d_in[2];
    const float* Wk = (const float*)d_in[3];
    const float* bk = (const float*)d_in[4];
    const float* Wv = (const float*)d_in[5];
    const float* bv = (const float*)d_in[6];
    const float* Wo = (const float*)d_in[7];
    const float* bo = (const float*)d_in[8];
    float* out = (float*)d_out;

    char* ws = (char*)d_ws;
    constexpr size_t SZ_ME = (size_t)Mq * Eq * 2;        // 8 MB
    u16*   Qb  = (u16*)  (ws + 0 * SZ_ME);
    u16*   Kb  = (u16*)  (ws + 1 * SZ_ME);
    u16*   KbT = (u16*)  (ws + 2 * SZ_ME);
    u16*   VbT = (u16*)  (ws + 3 * SZ_ME);
    u16*   Ob  = (u16*)  (ws + 4 * SZ_ME);
    u16*   KVT = (u16*)  (ws + 5 * SZ_ME);               // 8 MB bf16
    u16*   STb = (u16*)  (ws + 6 * SZ_ME);
    u16*   Xb  = (u16*)  (ws + 7 * SZ_ME);
    u16*   Wb0 = (u16*)  (ws + 8 * SZ_ME);               // [Wq|Wk|Wv|Wo] bf16
    u16* Wqkvb = Wb0;
    u16* Wob   = Wb0 + (size_t)3 * Eq * Eq;

    // 1) all bf16 conversions, one launch
    cvt_all_kernel<<<dim3(8192), dim3(256), 0, stream>>>(x, Wq, Wk, Wv, Wo, Xb, Wb0);

    // 2) fused QKV projection (M=4096, N=3072): 256^2 8-wave fine-phase, 192 blocks
    qkv8_kernel<<<dim3(192), dim3(512), 0, stream>>>(
        Xb, Wqkvb, bq, bk, bv, Qb, Kb, KbT, VbT);

    // 3) attention
    chunk_kv_kernel<<<dim3(BH * NC), dim3(64), 0, stream>>>(KbT, VbT, KVT);
    scan_kernel<<<dim3(BH * 16), dim3(256), 0, stream>>>(KVT, STb);
    attn_kernel<<<dim3(BH * NC), dim3(64), 0, stream>>>(Qb, Kb, VbT, STb, Ob);

    // 4) output projection (M=4096, N=1024): ring GEMM, 512 blocks (2/CU)
    oproj_kernel<<<dim3(512), dim3(256), 0, stream>>>(Ob, Wob, bo, out);
}

// Round 9
// 92.056 us; speedup vs baseline: 2.0293x; 1.0359x over previous
//
#include <hip/hip_runtime.h>
#include <hip/hip_bf16.h>
#include <cmath>

typedef unsigned short u16;
typedef __bf16 bf16x8 __attribute__((ext_vector_type(8)));
typedef float  f32x4  __attribute__((ext_vector_type(4)));
typedef float  f4     __attribute__((ext_vector_type(4)));
typedef u16    us4    __attribute__((ext_vector_type(4)));

#define DEVFN __device__ __forceinline__

static constexpr int Bq = 2, Nq = 2048, Eq = 1024;
static constexpr int Mq = Bq * Nq;        // 4096 tokens
static constexpr int CHK = 64;            // attention chunk
static constexpr int NC  = Nq / CHK;      // 32 chunks
static constexpr int BH  = Bq * 16;       // 32

DEVFN u16 f2b(float f) {                  // f32 -> bf16 (RNE), finite inputs
    union { float f; unsigned int u; } x; x.f = f;
    unsigned int r = x.u + 0x7fffu + ((x.u >> 16) & 1u);
    return (u16)(r >> 16);
}
DEVFN float b2f(u16 v) {
    union { unsigned int u; float f; } x; x.u = ((unsigned int)v) << 16; return x.f;
}

DEVFN void gl_lds16(const u16* g, u16* l) {  // async 16B global->LDS (dest: wave base + lane*16)
    __builtin_amdgcn_global_load_lds(
        (const __attribute__((address_space(1))) unsigned int*)(g),
        (__attribute__((address_space(3))) unsigned int*)(l),
        16, 0, 0);
}

// ---------------- all f32 -> bf16 converts in ONE launch ----------------
__global__ __launch_bounds__(256)
void cvt_all_kernel(const float* __restrict__ x,
                    const float* __restrict__ w0, const float* __restrict__ w1,
                    const float* __restrict__ w2, const float* __restrict__ w3,
                    u16* __restrict__ Xb, u16* __restrict__ Wb)
{
    const int blk = blockIdx.x;
    const float* s; u16* d; int i;
    if (blk < 4096) {
        i = blk * 256 + threadIdx.x;  s = x;  d = Xb;
    } else {
        const int wsel = (blk - 4096) >> 10;
        i = ((blk - 4096) & 1023) * 256 + threadIdx.x;
        s = (wsel == 0) ? w0 : (wsel == 1) ? w1 : (wsel == 2) ? w2 : w3;
        d = Wb + (size_t)wsel * (Eq * Eq);
    }
    f4 v = *reinterpret_cast<const f4*>(&s[(size_t)i * 4]);
    us4 p; p[0] = f2b(v[0]); p[1] = f2b(v[1]); p[2] = f2b(v[2]); p[3] = f2b(v[3]);
    *reinterpret_cast<us4*>(&d[(size_t)i * 4]) = p;
}

// ======== QKV ring GEMM: 128x128 tile, 4 waves, BK=32, ring-3 LDS, dup-free ========
// out[m][n] = act(X[m][:].W[n][:] + bias), N=3072 (seg 0=Q elu+1, 1=K ->Kb+KbT, 2=V ->VbT)
// Per iter t: stage tile t+2 (4 x gl_lds16) into buf[(t+2)%3]; ds_read+MFMA buf[t%3];
// s_waitcnt vmcnt(4) (tile t+1 landed, t+2 in flight); raw s_barrier.
// Swizzle sigma(row)=(row>>1)&3 on 16B slots, same involution both sides (R6: 0 conflicts).
__global__ __launch_bounds__(256)
void qkv_ring(const u16* __restrict__ X, const u16* __restrict__ W,
              const float* __restrict__ b0, const float* __restrict__ b1,
              const float* __restrict__ b2,
              u16* __restrict__ Qb, u16* __restrict__ Kb, u16* __restrict__ KbT,
              u16* __restrict__ VbT)
{
    constexpr int BUFU = 8192;                // 16KB: A 4096 u16 | B 4096 u16
    __shared__ u16 lds[3 * BUFU];             // 48KB -> 3 blocks/CU
    const int tid = threadIdx.x, wid = tid >> 6, lane = tid & 63;
    const int wr = (wid >> 1) * 64, wc = (wid & 1) * 64;
    const int fr = lane & 15, fq = lane >> 4;

    const int bid = blockIdx.x;               // grid 768 = 8 * 96 (XCD-bijective)
    const int fid = (bid & 7) * 96 + (bid >> 3);
    const int bx = fid % 24, by = fid / 24;
    const int m0 = by * 128, n0 = bx * 128;

    // staging: round = 256 thr x 16B = 64 rows (row = tid>>2, slot = tid&3)
    const int row0 = tid >> 2;
    const int sc   = ((tid & 3) ^ ((row0 >> 1) & 3)) * 8;   // swizzled source slot
    const u16* gA = X + (size_t)(m0 + row0) * 1024 + sc;
    const u16* gB = W + (size_t)(n0 + row0) * 1024 + sc;
    const int dw = wid * 512;                 // wave-uniform dest piece per round

    // fragment reads: same involution ( (base+fr)>>1 & 3 == (fr>>1)&3, base % 16 == 0 )
    const int fsw = (fq ^ ((fr >> 1) & 3)) << 3;
    int aoff[4], boff[4];
#pragma unroll
    for (int mi = 0; mi < 4; ++mi) aoff[mi] = (wr + mi * 16 + fr) * 32 + fsw;
#pragma unroll
    for (int ni = 0; ni < 4; ++ni) boff[ni] = 4096 + (wc + ni * 16 + fr) * 32 + fsw;

#define STAGE(kt, bs) do { u16* _b = lds + (bs) * BUFU;                        \
        gl_lds16(gA + (kt) * 32,             _b + dw);                         \
        gl_lds16(gA + (kt) * 32 + 64 * 1024, _b + 2048 + dw);                  \
        gl_lds16(gB + (kt) * 32,             _b + 4096 + dw);                  \
        gl_lds16(gB + (kt) * 32 + 64 * 1024, _b + 6144 + dw); } while (0)

    // prologue: tiles 0,1 staged (8 loads); wait tile0 (tile1's 4 stay in flight)
    STAGE(0, 0);
    STAGE(1, 1);
    asm volatile("s_waitcnt vmcnt(4)" ::: "memory");
    __builtin_amdgcn_sched_barrier(0);
    __builtin_amdgcn_s_barrier();

    f32x4 acc[4][4] = {};
    int cb = 0, sb = 2;

    for (int t = 0; t < 32; ++t) {
        if (t + 2 < 32) STAGE(t + 2, sb);
        const u16* buf = lds + cb * BUFU;
        bf16x8 af[4], bfv[4];
#pragma unroll
        for (int mi = 0; mi < 4; ++mi)
            af[mi] = *reinterpret_cast<const bf16x8*>(&buf[aoff[mi]]);
#pragma unroll
        for (int ni = 0; ni < 4; ++ni)
            bfv[ni] = *reinterpret_cast<const bf16x8*>(&buf[boff[ni]]);
        __builtin_amdgcn_s_setprio(1);
#pragma unroll
        for (int mi = 0; mi < 4; ++mi)
#pragma unroll
            for (int ni = 0; ni < 4; ++ni)
                acc[mi][ni] = __builtin_amdgcn_mfma_f32_16x16x32_bf16(
                    af[mi], bfv[ni], acc[mi][ni], 0, 0, 0);
        __builtin_amdgcn_s_setprio(0);
        // tile boundary: t+1 landed; keep t+2's 4 loads in flight
        if (t < 30)       asm volatile("s_waitcnt vmcnt(4)" ::: "memory");
        else if (t == 30) asm volatile("s_waitcnt vmcnt(0)" ::: "memory");
        __builtin_amdgcn_sched_barrier(0);
        __builtin_amdgcn_s_barrier();
        cb = (cb == 2) ? 0 : cb + 1;
        sb = (sb == 2) ? 0 : sb + 1;
    }
#undef STAGE

    const int seg = n0 >> 10;                          // 0=q 1=k 2=v
    const float* bp = (seg == 0) ? b0 : (seg == 1) ? b1 : b2;
#pragma unroll
    for (int mi = 0; mi < 4; ++mi)
#pragma unroll
        for (int ni = 0; ni < 4; ++ni) {
            const int nl    = (n0 & 1023) + wc + ni * 16 + fr;
            const int mbase = m0 + wr + mi * 16 + fq * 4;
            const float bn  = bp[nl];
            float vr[4];
#pragma unroll
            for (int r = 0; r < 4; ++r) {
                float v = acc[mi][ni][r] + bn;
                if (seg < 2) v = (v > 0.f) ? (v + 1.f) : __expf(v);  // elu+1
                vr[r] = v;
            }
            if (seg == 0) {
#pragma unroll
                for (int r = 0; r < 4; ++r)
                    Qb[(size_t)(mbase + r) * 1024 + nl] = f2b(vr[r]);
            } else {
                us4 pk;
#pragma unroll
                for (int r = 0; r < 4; ++r) pk[r] = f2b(vr[r]);
                const int bb = mbase >> 11, nt = mbase & 2047;
                const int hh = nl >> 6,     dd = nl & 63;
                u16* T = (seg == 1) ? KbT : VbT;
                *reinterpret_cast<us4*>(
                    &T[((size_t)(bb * 16 + hh) * 64 + dd) * 2048 + nt]) = pk;
                if (seg == 1) {
#pragma unroll
                    for (int r = 0; r < 4; ++r)
                        Kb[(size_t)(mbase + r) * 1024 + nl] = f2b(vr[r]);
                }
            }
        }
}

// ======== O-proj: 64x128 tile, 4 waves, BK=32, ring-3, dup-free (R8, verified) ========
__global__ __launch_bounds__(256)
void oproj_kernel(const u16* __restrict__ X, const u16* __restrict__ W,
                  const float* __restrict__ b0, float* __restrict__ outF)
{
    constexpr int BUFU = (64 + 128) * 32;     // 6144 u16 = 12KB per buffer
    __shared__ u16 lds[3 * BUFU];             // 36KB
    const int tid = threadIdx.x, wid = tid >> 6, lane = tid & 63;
    const int wr = (wid >> 1) * 32, wc = (wid & 1) * 64;
    const int fr = lane & 15, fq = lane >> 4;

    const int bid = blockIdx.x;               // grid 512 = 8 * 64
    const int fid = (bid & 7) * 64 + (bid >> 3);
    const int bx = fid & 7, by = fid >> 3;
    const int m0 = by * 64, n0 = bx * 128;

    const int ra = tid >> 2;
    const int sc = ((tid & 3) ^ ((tid >> 3) & 3)) * 8;
    const u16* gA = X + (size_t)(m0 + ra) * 1024 + sc;
    const u16* gB = W + (size_t)(n0 + ra) * 1024 + sc;
    const int dw = wid * 512;

    const int fsw = (fq ^ ((fr >> 1) & 3)) << 3;
    int aoff[2], boff[4];
#pragma unroll
    for (int mi = 0; mi < 2; ++mi) aoff[mi] = (wr + mi * 16 + fr) * 32 + fsw;
#pragma unroll
    for (int ni = 0; ni < 4; ++ni) boff[ni] = 2048 + (wc + ni * 16 + fr) * 32 + fsw;

#define STAGE(kt, bs) do { u16* _b = lds + (bs) * BUFU;                          \
        gl_lds16(gA + (kt) * 32,             _b + dw);                           \
        gl_lds16(gB + (kt) * 32,             _b + 2048 + dw);                    \
        gl_lds16(gB + (kt) * 32 + 64 * 1024, _b + 4096 + dw); } while (0)

    STAGE(0, 0);
    STAGE(1, 1);
    asm volatile("s_waitcnt vmcnt(3)" ::: "memory");
    __builtin_amdgcn_sched_barrier(0);
    __builtin_amdgcn_s_barrier();

    f32x4 acc[2][4] = {};
    int cb = 0, sb = 2;

    for (int t = 0; t < 32; ++t) {
        if (t + 2 < 32) STAGE(t + 2, sb);
        const u16* buf = lds + cb * BUFU;
        bf16x8 af[2], bfv[4];
#pragma unroll
        for (int mi = 0; mi < 2; ++mi)
            af[mi] = *reinterpret_cast<const bf16x8*>(&buf[aoff[mi]]);
#pragma unroll
        for (int ni = 0; ni < 4; ++ni)
            bfv[ni] = *reinterpret_cast<const bf16x8*>(&buf[boff[ni]]);
        __builtin_amdgcn_s_setprio(1);
#pragma unroll
        for (int mi = 0; mi < 2; ++mi)
#pragma unroll
            for (int ni = 0; ni < 4; ++ni)
                acc[mi][ni] = __builtin_amdgcn_mfma_f32_16x16x32_bf16(
                    af[mi], bfv[ni], acc[mi][ni], 0, 0, 0);
        __builtin_amdgcn_s_setprio(0);
        if (t < 30)       asm volatile("s_waitcnt vmcnt(3)" ::: "memory");
        else if (t == 30) asm volatile("s_waitcnt vmcnt(0)" ::: "memory");
        __builtin_amdgcn_sched_barrier(0);
        __builtin_amdgcn_s_barrier();
        cb = (cb == 2) ? 0 : cb + 1;
        sb = (sb == 2) ? 0 : sb + 1;
    }
#undef STAGE

#pragma unroll
    for (int mi = 0; mi < 2; ++mi)
#pragma unroll
        for (int ni = 0; ni < 4; ++ni) {
            const int n     = n0 + wc + ni * 16 + fr;
            const int mbase = m0 + wr + mi * 16 + fq * 4;
            const float bn  = b0[n];
#pragma unroll
            for (int r = 0; r < 4; ++r)
                outF[(size_t)(mbase + r) * 1024 + n] = acc[mi][ni][r] + bn;
        }
}

// ---------------- per-chunk KV^T = v^T @ k: KVT[de][dk], bf16 out ----------------
__global__ __launch_bounds__(64)
void chunk_kv_kernel(const u16* __restrict__ KbT, const u16* __restrict__ VbT,
                     u16* __restrict__ KVT)
{
    const int blk = blockIdx.x;          // bh*NC + c
    const int bh = blk >> 5, c = blk & 31;
    const int lane = threadIdx.x;
    const int fr = lane & 15, fq = lane >> 4, fk = fq * 8;
    const u16* kt = KbT + (size_t)bh * 64 * 2048;
    const u16* vt = VbT + (size_t)bh * 64 * 2048;

    bf16x8 a[4][2], b[4][2];             // a = V rows (de), b = K rows (dk)
#pragma unroll
    for (int mi = 0; mi < 4; ++mi)
#pragma unroll
        for (int kh = 0; kh < 2; ++kh)
            a[mi][kh] = *reinterpret_cast<const bf16x8*>(
                &vt[(size_t)(mi * 16 + fr) * 2048 + c * 64 + kh * 32 + fk]);
#pragma unroll
    for (int ni = 0; ni < 4; ++ni)
#pragma unroll
        for (int kh = 0; kh < 2; ++kh)
            b[ni][kh] = *reinterpret_cast<const bf16x8*>(
                &kt[(size_t)(ni * 16 + fr) * 2048 + c * 64 + kh * 32 + fk]);

    f32x4 acc[4][4] = {};
    __builtin_amdgcn_s_setprio(1);
#pragma unroll
    for (int mi = 0; mi < 4; ++mi)
#pragma unroll
        for (int ni = 0; ni < 4; ++ni)
#pragma unroll
            for (int kh = 0; kh < 2; ++kh)
                acc[mi][ni] = __builtin_amdgcn_mfma_f32_16x16x32_bf16(
                    a[mi][kh], b[ni][kh], acc[mi][ni], 0, 0, 0);
    __builtin_amdgcn_s_setprio(0);

    u16* out = KVT + (size_t)blk * 4096;   // [de][dk] bf16
#pragma unroll
    for (int mi = 0; mi < 4; ++mi)
#pragma unroll
        for (int ni = 0; ni < 4; ++ni)
#pragma unroll
            for (int r = 0; r < 4; ++r)
                out[(mi * 16 + fq * 4 + r) * 64 + ni * 16 + fr] = f2b(acc[mi][ni][r]);
}

// ---------------- elementwise exclusive scan over chunks (bf16 in/out) ----------------
__global__ __launch_bounds__(256)
void scan_kernel(const u16* __restrict__ KVT, u16* __restrict__ STb)
{
    const int bh = blockIdx.x >> 4, sl = blockIdx.x & 15;
    const int el = sl * 256 + threadIdx.x;              // element of [de][dk]
    const u16* src = KVT + (size_t)bh * NC * 4096 + el;
    u16*      dst  = STb + (size_t)bh * NC * 4096 + el;
    float run = 0.f;
#pragma unroll 4
    for (int c = 0; c < NC; ++c) {
        dst[(size_t)c * 4096] = f2b(run);               // exclusive prefix
        run += b2f(src[(size_t)c * 4096]);
    }
}

// ---------------- per-chunk attention output ----------------
__global__ __launch_bounds__(64)
void attn_kernel(const u16* __restrict__ Qb, const u16* __restrict__ Kb,
                 const u16* __restrict__ VbT, const u16* __restrict__ STb,
                 u16* __restrict__ Ob)
{
    __shared__ u16 P[64 * 72];   // stride 72 u16 = 144B: 16B-aligned, 2-way banks
    const int blk = blockIdx.x;
    const int bh = blk >> 5, c = blk & 31;
    const int b = bh >> 4, h = bh & 15;
    const int lane = threadIdx.x;
    const int fr = lane & 15, fq = lane >> 4, fk = fq * 8;
    const int tok0 = b * 2048 + c * 64;

    bf16x8 qa[4][2];
#pragma unroll
    for (int mi = 0; mi < 4; ++mi)
#pragma unroll
        for (int kh = 0; kh < 2; ++kh)
            qa[mi][kh] = *reinterpret_cast<const bf16x8*>(
                &Qb[(size_t)(tok0 + mi * 16 + fr) * 1024 + h * 64 + kh * 32 + fk]);

    // P = causal-mask(q @ k^T) -> LDS bf16
    {
        bf16x8 kb[4][2];
#pragma unroll
        for (int si = 0; si < 4; ++si)
#pragma unroll
            for (int kh = 0; kh < 2; ++kh)
                kb[si][kh] = *reinterpret_cast<const bf16x8*>(
                    &Kb[(size_t)(tok0 + si * 16 + fr) * 1024 + h * 64 + kh * 32 + fk]);
        f32x4 p[4][4] = {};
        __builtin_amdgcn_s_setprio(1);
#pragma unroll
        for (int mi = 0; mi < 4; ++mi)
#pragma unroll
            for (int si = 0; si < 4; ++si)
#pragma unroll
                for (int kh = 0; kh < 2; ++kh)
                    p[mi][si] = __builtin_amdgcn_mfma_f32_16x16x32_bf16(
                        qa[mi][kh], kb[si][kh], p[mi][si], 0, 0, 0);
        __builtin_amdgcn_s_setprio(0);
#pragma unroll
        for (int mi = 0; mi < 4; ++mi)
#pragma unroll
            for (int si = 0; si < 4; ++si)
#pragma unroll
                for (int r = 0; r < 4; ++r) {
                    int t = mi * 16 + fq * 4 + r;
                    int s = si * 16 + fr;
                    float v = (s <= t) ? p[mi][si][r] : 0.0f;
                    P[t * 72 + s] = f2b(v);
                }
    }
    __syncthreads();

    f32x4 acc[4][4] = {};
    // acc = q @ ST   (STb[de][dk], dk-contiguous)
    {
        const u16* st = STb + (size_t)blk * 4096;
        bf16x8 sb[4][2];
#pragma unroll
        for (int ni = 0; ni < 4; ++ni)
#pragma unroll
            for (int kh = 0; kh < 2; ++kh)
                sb[ni][kh] = *reinterpret_cast<const bf16x8*>(
                    &st[(ni * 16 + fr) * 64 + kh * 32 + fk]);
        __builtin_amdgcn_s_setprio(1);
#pragma unroll
        for (int mi = 0; mi < 4; ++mi)
#pragma unroll
            for (int ni = 0; ni < 4; ++ni)
#pragma unroll
                for (int kh = 0; kh < 2; ++kh)
                    acc[mi][ni] = __builtin_amdgcn_mfma_f32_16x16x32_bf16(
                        qa[mi][kh], sb[ni][kh], acc[mi][ni], 0, 0, 0);
        __builtin_amdgcn_s_setprio(0);
    }
    // acc += P @ v
    {
        const u16* vt = VbT + (size_t)bh * 64 * 2048;
#pragma unroll
        for (int sh = 0; sh < 2; ++sh) {
            bf16x8 pa[4], vb[4];
#pragma unroll
            for (int mi = 0; mi < 4; ++mi)
                pa[mi] = *reinterpret_cast<const bf16x8*>(
                    &P[(mi * 16 + fr) * 72 + sh * 32 + fk]);
#pragma unroll
            for (int ni = 0; ni < 4; ++ni)
                vb[ni] = *reinterpret_cast<const bf16x8*>(
                    &vt[(size_t)(ni * 16 + fr) * 2048 + c * 64 + sh * 32 + fk]);
            __builtin_amdgcn_s_setprio(1);
#pragma unroll
            for (int mi = 0; mi < 4; ++mi)
#pragma unroll
                for (int ni = 0; ni < 4; ++ni)
                    acc[mi][ni] = __builtin_amdgcn_mfma_f32_16x16x32_bf16(
                        pa[mi], vb[ni], acc[mi][ni], 0, 0, 0);
            __builtin_amdgcn_s_setprio(0);
        }
    }
    // write token-major bf16 O
#pragma unroll
    for (int mi = 0; mi < 4; ++mi)
#pragma unroll
        for (int ni = 0; ni < 4; ++ni)
#pragma unroll
            for (int r = 0; r < 4; ++r) {
                int t = tok0 + mi * 16 + fq * 4 + r;
                int n = h * 64 + ni * 16 + fr;
                Ob[(size_t)t * 1024 + n] = f2b(acc[mi][ni][r]);
            }
}

extern "C" void kernel_launch(void* const* d_in, const int* in_sizes, int n_in,
                              void* d_out, int out_size, void* d_ws, size_t ws_size,
                              hipStream_t stream)
{
    (void)in_sizes; (void)n_in; (void)out_size; (void)ws_size;
    const float* x  = (const float*)d_in[0];
    const float* Wq = (const float*)d_in[1];
    const float* bq = (const float*)d_in[2];
    const float* Wk = (const float*)d_in[3];
    const float* bk = (const float*)d_in[4];
    const float* Wv = (const float*)d_in[5];
    const float* bv = (const float*)d_in[6];
    const float* Wo = (const float*)d_in[7];
    const float* bo = (const float*)d_in[8];
    float* out = (float*)d_out;

    char* ws = (char*)d_ws;
    constexpr size_t SZ_ME = (size_t)Mq * Eq * 2;        // 8 MB
    u16*   Qb  = (u16*)  (ws + 0 * SZ_ME);
    u16*   Kb  = (u16*)  (ws + 1 * SZ_ME);
    u16*   KbT = (u16*)  (ws + 2 * SZ_ME);
    u16*   VbT = (u16*)  (ws + 3 * SZ_ME);
    u16*   Ob  = (u16*)  (ws + 4 * SZ_ME);
    u16*   KVT = (u16*)  (ws + 5 * SZ_ME);               // 8 MB bf16
    u16*   STb = (u16*)  (ws + 6 * SZ_ME);
    u16*   Xb  = (u16*)  (ws + 7 * SZ_ME);
    u16*   Wb0 = (u16*)  (ws + 8 * SZ_ME);               // [Wq|Wk|Wv|Wo] bf16
    u16* Wqkvb = Wb0;
    u16* Wob   = Wb0 + (size_t)3 * Eq * Eq;

    // 1) all bf16 conversions, one launch
    cvt_all_kernel<<<dim3(8192), dim3(256), 0, stream>>>(x, Wq, Wk, Wv, Wo, Xb, Wb0);

    // 2) fused QKV projection (M=4096, N=3072): ring GEMM, 768 blocks (3/CU)
    qkv_ring<<<dim3(768), dim3(256), 0, stream>>>(
        Xb, Wqkvb, bq, bk, bv, Qb, Kb, KbT, VbT);

    // 3) attention
    chunk_kv_kernel<<<dim3(BH * NC), dim3(64), 0, stream>>>(KbT, VbT, KVT);
    scan_kernel<<<dim3(BH * 16), dim3(256), 0, stream>>>(KVT, STb);
    attn_kernel<<<dim3(BH * NC), dim3(64), 0, stream>>>(Qb, Kb, VbT, STb, Ob);

    // 4) output projection (M=4096, N=1024): ring GEMM, 512 blocks (2/CU)
    oproj_kernel<<<dim3(512), dim3(256), 0, stream>>>(Ob, Wob, bo, out);
}

// Round 10
// 89.902 us; speedup vs baseline: 2.0779x; 1.0240x over previous
//
#include <hip/hip_runtime.h>
#include <hip/hip_bf16.h>
#include <cmath>

typedef unsigned short u16;
typedef __bf16 bf16x8 __attribute__((ext_vector_type(8)));
typedef float  f32x4  __attribute__((ext_vector_type(4)));
typedef float  f4     __attribute__((ext_vector_type(4)));
typedef u16    us4    __attribute__((ext_vector_type(4)));

#define DEVFN __device__ __forceinline__

static constexpr int Bq = 2, Nq = 2048, Eq = 1024;
static constexpr int Mq = Bq * Nq;        // 4096 tokens
static constexpr int CHK = 64;            // attention chunk
static constexpr int NC  = Nq / CHK;      // 32 chunks
static constexpr int BH  = Bq * 16;       // 32

DEVFN u16 f2b(float f) {                  // f32 -> bf16 (RNE), finite inputs
    union { float f; unsigned int u; } x; x.f = f;
    unsigned int r = x.u + 0x7fffu + ((x.u >> 16) & 1u);
    return (u16)(r >> 16);
}
DEVFN float b2f(u16 v) {
    union { unsigned int u; float f; } x; x.u = ((unsigned int)v) << 16; return x.f;
}

DEVFN void gl_lds16(const u16* g, u16* l) {  // async 16B global->LDS (dest: wave base + lane*16)
    __builtin_amdgcn_global_load_lds(
        (const __attribute__((address_space(1))) unsigned int*)(g),
        (__attribute__((address_space(3))) unsigned int*)(l),
        16, 0, 0);
}

// ---------------- all f32 -> bf16 converts in ONE launch ----------------
__global__ __launch_bounds__(256)
void cvt_all_kernel(const float* __restrict__ x,
                    const float* __restrict__ w0, const float* __restrict__ w1,
                    const float* __restrict__ w2, const float* __restrict__ w3,
                    u16* __restrict__ Xb, u16* __restrict__ Wb)
{
    const int blk = blockIdx.x;
    const float* s; u16* d; int i;
    if (blk < 4096) {
        i = blk * 256 + threadIdx.x;  s = x;  d = Xb;
    } else {
        const int wsel = (blk - 4096) >> 10;
        i = ((blk - 4096) & 1023) * 256 + threadIdx.x;
        s = (wsel == 0) ? w0 : (wsel == 1) ? w1 : (wsel == 2) ? w2 : w3;
        d = Wb + (size_t)wsel * (Eq * Eq);
    }
    f4 v = *reinterpret_cast<const f4*>(&s[(size_t)i * 4]);
    us4 p; p[0] = f2b(v[0]); p[1] = f2b(v[1]); p[2] = f2b(v[2]); p[3] = f2b(v[3]);
    *reinterpret_cast<us4*>(&d[(size_t)i * 4]) = p;
}

// ======== QKV ring GEMM: 128x128 tile, 8 waves (32x64 each), BK=32, ring-3 ========
// Same ring/barrier/vmcnt schedule as R9 (proven), but 512 threads -> 24 waves/CU
// (6/SIMD) for latency hiding. Wave tile 32x64: 2 A-frags, 4 B-frags, 8 MFMA/tile.
// Staging: one 512-thr round = full 128x32 matrix; 2 gl_lds16/tile; steady vmcnt(2).
// Swizzle sigma(row)=(row>>1)&3 on 16B slots, both sides (R6: 0 conflicts).
__global__ __launch_bounds__(512, 4)
void qkv_ring(const u16* __restrict__ X, const u16* __restrict__ W,
              const float* __restrict__ b0, const float* __restrict__ b1,
              const float* __restrict__ b2,
              u16* __restrict__ Qb, u16* __restrict__ Kb, u16* __restrict__ KbT,
              u16* __restrict__ VbT)
{
    constexpr int BUFU = 8192;                // 16KB: A 4096 u16 | B 4096 u16
    __shared__ u16 lds[3 * BUFU];             // 48KB -> 3 blocks/CU
    const int tid = threadIdx.x, wid = tid >> 6, lane = tid & 63;
    const int wr = (wid >> 1) * 32, wc = (wid & 1) * 64;   // wave: 32 rows x 64 cols
    const int fr = lane & 15, fq = lane >> 4;

    const int bid = blockIdx.x;               // grid 768 = 8 * 96 (XCD-bijective)
    const int fid = (bid & 7) * 96 + (bid >> 3);
    const int bx = fid % 24, by = fid / 24;
    const int m0 = by * 128, n0 = bx * 128;

    // staging: one round = 512 thr x 16B = 128 rows x 4 slots (full matrix)
    const int row0 = tid >> 2;
    const int sc   = ((tid & 3) ^ ((row0 >> 1) & 3)) * 8;   // swizzled source slot
    const u16* gA = X + (size_t)(m0 + row0) * 1024 + sc;
    const u16* gB = W + (size_t)(n0 + row0) * 1024 + sc;
    const int dw = wid * 512;                 // wave-uniform dest piece (1KB/wave)

    // fragment reads: same involution on read side
    const int fsw = (fq ^ ((fr >> 1) & 3)) << 3;
    int aoff[2], boff[4];
#pragma unroll
    for (int mi = 0; mi < 2; ++mi) aoff[mi] = (wr + mi * 16 + fr) * 32 + fsw;
#pragma unroll
    for (int ni = 0; ni < 4; ++ni) boff[ni] = 4096 + (wc + ni * 16 + fr) * 32 + fsw;

#define STAGE(kt, bs) do { u16* _b = lds + (bs) * BUFU;                        \
        gl_lds16(gA + (kt) * 32, _b + dw);                                     \
        gl_lds16(gB + (kt) * 32, _b + 4096 + dw); } while (0)

    // prologue: tiles 0,1 staged (4 loads); wait tile0 (tile1's 2 stay in flight)
    STAGE(0, 0);
    STAGE(1, 1);
    asm volatile("s_waitcnt vmcnt(2)" ::: "memory");
    __builtin_amdgcn_sched_barrier(0);
    __builtin_amdgcn_s_barrier();

    f32x4 acc[2][4] = {};
    int cb = 0, sb = 2;

    for (int t = 0; t < 32; ++t) {
        if (t + 2 < 32) STAGE(t + 2, sb);
        const u16* buf = lds + cb * BUFU;
        bf16x8 af[2], bfv[4];
#pragma unroll
        for (int mi = 0; mi < 2; ++mi)
            af[mi] = *reinterpret_cast<const bf16x8*>(&buf[aoff[mi]]);
#pragma unroll
        for (int ni = 0; ni < 4; ++ni)
            bfv[ni] = *reinterpret_cast<const bf16x8*>(&buf[boff[ni]]);
        __builtin_amdgcn_s_setprio(1);
#pragma unroll
        for (int mi = 0; mi < 2; ++mi)
#pragma unroll
            for (int ni = 0; ni < 4; ++ni)
                acc[mi][ni] = __builtin_amdgcn_mfma_f32_16x16x32_bf16(
                    af[mi], bfv[ni], acc[mi][ni], 0, 0, 0);
        __builtin_amdgcn_s_setprio(0);
        // tile boundary: t+1 landed; keep t+2's 2 loads in flight
        if (t < 30)       asm volatile("s_waitcnt vmcnt(2)" ::: "memory");
        else if (t == 30) asm volatile("s_waitcnt vmcnt(0)" ::: "memory");
        __builtin_amdgcn_sched_barrier(0);
        __builtin_amdgcn_s_barrier();
        cb = (cb == 2) ? 0 : cb + 1;
        sb = (sb == 2) ? 0 : sb + 1;
    }
#undef STAGE

    const int nw  = n0 + wc;                           // 64-aligned, seg-uniform
    const int seg = nw >> 10;                          // 0=q 1=k 2=v
    const float* bp = (seg == 0) ? b0 : (seg == 1) ? b1 : b2;
#pragma unroll
    for (int mi = 0; mi < 2; ++mi)
#pragma unroll
        for (int ni = 0; ni < 4; ++ni) {
            const int nl    = (nw & 1023) + ni * 16 + fr;
            const int mbase = m0 + wr + mi * 16 + fq * 4;
            const float bn  = bp[nl];
            float vr[4];
#pragma unroll
            for (int r = 0; r < 4; ++r) {
                float v = acc[mi][ni][r] + bn;
                if (seg < 2) v = (v > 0.f) ? (v + 1.f) : __expf(v);  // elu+1
                vr[r] = v;
            }
            if (seg == 0) {
#pragma unroll
                for (int r = 0; r < 4; ++r)
                    Qb[(size_t)(mbase + r) * 1024 + nl] = f2b(vr[r]);
            } else {
                us4 pk;
#pragma unroll
                for (int r = 0; r < 4; ++r) pk[r] = f2b(vr[r]);
                const int bb = mbase >> 11, nt = mbase & 2047;
                const int hh = nl >> 6,     dd = nl & 63;
                u16* T = (seg == 1) ? KbT : VbT;
                *reinterpret_cast<us4*>(
                    &T[((size_t)(bb * 16 + hh) * 64 + dd) * 2048 + nt]) = pk;
                if (seg == 1) {
#pragma unroll
                    for (int r = 0; r < 4; ++r)
                        Kb[(size_t)(mbase + r) * 1024 + nl] = f2b(vr[r]);
                }
            }
        }
}

// ======== O-proj: 64x128 tile, 4 waves, BK=32, ring-3, dup-free (R8, verified) ========
__global__ __launch_bounds__(256)
void oproj_kernel(const u16* __restrict__ X, const u16* __restrict__ W,
                  const float* __restrict__ b0, float* __restrict__ outF)
{
    constexpr int BUFU = (64 + 128) * 32;     // 6144 u16 = 12KB per buffer
    __shared__ u16 lds[3 * BUFU];             // 36KB
    const int tid = threadIdx.x, wid = tid >> 6, lane = tid & 63;
    const int wr = (wid >> 1) * 32, wc = (wid & 1) * 64;
    const int fr = lane & 15, fq = lane >> 4;

    const int bid = blockIdx.x;               // grid 512 = 8 * 64
    const int fid = (bid & 7) * 64 + (bid >> 3);
    const int bx = fid & 7, by = fid >> 3;
    const int m0 = by * 64, n0 = bx * 128;

    const int ra = tid >> 2;
    const int sc = ((tid & 3) ^ ((tid >> 3) & 3)) * 8;
    const u16* gA = X + (size_t)(m0 + ra) * 1024 + sc;
    const u16* gB = W + (size_t)(n0 + ra) * 1024 + sc;
    const int dw = wid * 512;

    const int fsw = (fq ^ ((fr >> 1) & 3)) << 3;
    int aoff[2], boff[4];
#pragma unroll
    for (int mi = 0; mi < 2; ++mi) aoff[mi] = (wr + mi * 16 + fr) * 32 + fsw;
#pragma unroll
    for (int ni = 0; ni < 4; ++ni) boff[ni] = 2048 + (wc + ni * 16 + fr) * 32 + fsw;

#define STAGE(kt, bs) do { u16* _b = lds + (bs) * BUFU;                          \
        gl_lds16(gA + (kt) * 32,             _b + dw);                           \
        gl_lds16(gB + (kt) * 32,             _b + 2048 + dw);                    \
        gl_lds16(gB + (kt) * 32 + 64 * 1024, _b + 4096 + dw); } while (0)

    STAGE(0, 0);
    STAGE(1, 1);
    asm volatile("s_waitcnt vmcnt(3)" ::: "memory");
    __builtin_amdgcn_sched_barrier(0);
    __builtin_amdgcn_s_barrier();

    f32x4 acc[2][4] = {};
    int cb = 0, sb = 2;

    for (int t = 0; t < 32; ++t) {
        if (t + 2 < 32) STAGE(t + 2, sb);
        const u16* buf = lds + cb * BUFU;
        bf16x8 af[2], bfv[4];
#pragma unroll
        for (int mi = 0; mi < 2; ++mi)
            af[mi] = *reinterpret_cast<const bf16x8*>(&buf[aoff[mi]]);
#pragma unroll
        for (int ni = 0; ni < 4; ++ni)
            bfv[ni] = *reinterpret_cast<const bf16x8*>(&buf[boff[ni]]);
        __builtin_amdgcn_s_setprio(1);
#pragma unroll
        for (int mi = 0; mi < 2; ++mi)
#pragma unroll
            for (int ni = 0; ni < 4; ++ni)
                acc[mi][ni] = __builtin_amdgcn_mfma_f32_16x16x32_bf16(
                    af[mi], bfv[ni], acc[mi][ni], 0, 0, 0);
        __builtin_amdgcn_s_setprio(0);
        if (t < 30)       asm volatile("s_waitcnt vmcnt(3)" ::: "memory");
        else if (t == 30) asm volatile("s_waitcnt vmcnt(0)" ::: "memory");
        __builtin_amdgcn_sched_barrier(0);
        __builtin_amdgcn_s_barrier();
        cb = (cb == 2) ? 0 : cb + 1;
        sb = (sb == 2) ? 0 : sb + 1;
    }
#undef STAGE

#pragma unroll
    for (int mi = 0; mi < 2; ++mi)
#pragma unroll
        for (int ni = 0; ni < 4; ++ni) {
            const int n     = n0 + wc + ni * 16 + fr;
            const int mbase = m0 + wr + mi * 16 + fq * 4;
            const float bn  = b0[n];
#pragma unroll
            for (int r = 0; r < 4; ++r)
                outF[(size_t)(mbase + r) * 1024 + n] = acc[mi][ni][r] + bn;
        }
}

// ---------------- per-chunk KV^T = v^T @ k: KVT[de][dk], bf16 out ----------------
__global__ __launch_bounds__(64)
void chunk_kv_kernel(const u16* __restrict__ KbT, const u16* __restrict__ VbT,
                     u16* __restrict__ KVT)
{
    const int blk = blockIdx.x;          // bh*NC + c
    const int bh = blk >> 5, c = blk & 31;
    const int lane = threadIdx.x;
    const int fr = lane & 15, fq = lane >> 4, fk = fq * 8;
    const u16* kt = KbT + (size_t)bh * 64 * 2048;
    const u16* vt = VbT + (size_t)bh * 64 * 2048;

    bf16x8 a[4][2], b[4][2];             // a = V rows (de), b = K rows (dk)
#pragma unroll
    for (int mi = 0; mi < 4; ++mi)
#pragma unroll
        for (int kh = 0; kh < 2; ++kh)
            a[mi][kh] = *reinterpret_cast<const bf16x8*>(
                &vt[(size_t)(mi * 16 + fr) * 2048 + c * 64 + kh * 32 + fk]);
#pragma unroll
    for (int ni = 0; ni < 4; ++ni)
#pragma unroll
        for (int kh = 0; kh < 2; ++kh)
            b[ni][kh] = *reinterpret_cast<const bf16x8*>(
                &kt[(size_t)(ni * 16 + fr) * 2048 + c * 64 + kh * 32 + fk]);

    f32x4 acc[4][4] = {};
    __builtin_amdgcn_s_setprio(1);
#pragma unroll
    for (int mi = 0; mi < 4; ++mi)
#pragma unroll
        for (int ni = 0; ni < 4; ++ni)
#pragma unroll
            for (int kh = 0; kh < 2; ++kh)
                acc[mi][ni] = __builtin_amdgcn_mfma_f32_16x16x32_bf16(
                    a[mi][kh], b[ni][kh], acc[mi][ni], 0, 0, 0);
    __builtin_amdgcn_s_setprio(0);

    u16* out = KVT + (size_t)blk * 4096;   // [de][dk] bf16
#pragma unroll
    for (int mi = 0; mi < 4; ++mi)
#pragma unroll
        for (int ni = 0; ni < 4; ++ni)
#pragma unroll
            for (int r = 0; r < 4; ++r)
                out[(mi * 16 + fq * 4 + r) * 64 + ni * 16 + fr] = f2b(acc[mi][ni][r]);
}

// ---------------- elementwise exclusive scan over chunks (bf16 in/out) ----------------
__global__ __launch_bounds__(256)
void scan_kernel(const u16* __restrict__ KVT, u16* __restrict__ STb)
{
    const int bh = blockIdx.x >> 4, sl = blockIdx.x & 15;
    const int el = sl * 256 + threadIdx.x;              // element of [de][dk]
    const u16* src = KVT + (size_t)bh * NC * 4096 + el;
    u16*      dst  = STb + (size_t)bh * NC * 4096 + el;
    float run = 0.f;
#pragma unroll 4
    for (int c = 0; c < NC; ++c) {
        dst[(size_t)c * 4096] = f2b(run);               // exclusive prefix
        run += b2f(src[(size_t)c * 4096]);
    }
}

// ---------------- per-chunk attention output ----------------
__global__ __launch_bounds__(64)
void attn_kernel(const u16* __restrict__ Qb, const u16* __restrict__ Kb,
                 const u16* __restrict__ VbT, const u16* __restrict__ STb,
                 u16* __restrict__ Ob)
{
    __shared__ u16 P[64 * 72];   // stride 72 u16 = 144B: 16B-aligned, 2-way banks
    const int blk = blockIdx.x;
    const int bh = blk >> 5, c = blk & 31;
    const int b = bh >> 4, h = bh & 15;
    const int lane = threadIdx.x;
    const int fr = lane & 15, fq = lane >> 4, fk = fq * 8;
    const int tok0 = b * 2048 + c * 64;

    bf16x8 qa[4][2];
#pragma unroll
    for (int mi = 0; mi < 4; ++mi)
#pragma unroll
        for (int kh = 0; kh < 2; ++kh)
            qa[mi][kh] = *reinterpret_cast<const bf16x8*>(
                &Qb[(size_t)(tok0 + mi * 16 + fr) * 1024 + h * 64 + kh * 32 + fk]);

    // P = causal-mask(q @ k^T) -> LDS bf16
    {
        bf16x8 kb[4][2];
#pragma unroll
        for (int si = 0; si < 4; ++si)
#pragma unroll
            for (int kh = 0; kh < 2; ++kh)
                kb[si][kh] = *reinterpret_cast<const bf16x8*>(
                    &Kb[(size_t)(tok0 + si * 16 + fr) * 1024 + h * 64 + kh * 32 + fk]);
        f32x4 p[4][4] = {};
        __builtin_amdgcn_s_setprio(1);
#pragma unroll
        for (int mi = 0; mi < 4; ++mi)
#pragma unroll
            for (int si = 0; si < 4; ++si)
#pragma unroll
                for (int kh = 0; kh < 2; ++kh)
                    p[mi][si] = __builtin_amdgcn_mfma_f32_16x16x32_bf16(
                        qa[mi][kh], kb[si][kh], p[mi][si], 0, 0, 0);
        __builtin_amdgcn_s_setprio(0);
#pragma unroll
        for (int mi = 0; mi < 4; ++mi)
#pragma unroll
            for (int si = 0; si < 4; ++si)
#pragma unroll
                for (int r = 0; r < 4; ++r) {
                    int t = mi * 16 + fq * 4 + r;
                    int s = si * 16 + fr;
                    float v = (s <= t) ? p[mi][si][r] : 0.0f;
                    P[t * 72 + s] = f2b(v);
                }
    }
    __syncthreads();

    f32x4 acc[4][4] = {};
    // acc = q @ ST   (STb[de][dk], dk-contiguous)
    {
        const u16* st = STb + (size_t)blk * 4096;
        bf16x8 sb[4][2];
#pragma unroll
        for (int ni = 0; ni < 4; ++ni)
#pragma unroll
            for (int kh = 0; kh < 2; ++kh)
                sb[ni][kh] = *reinterpret_cast<const bf16x8*>(
                    &st[(ni * 16 + fr) * 64 + kh * 32 + fk]);
        __builtin_amdgcn_s_setprio(1);
#pragma unroll
        for (int mi = 0; mi < 4; ++mi)
#pragma unroll
            for (int ni = 0; ni < 4; ++ni)
#pragma unroll
                for (int kh = 0; kh < 2; ++kh)
                    acc[mi][ni] = __builtin_amdgcn_mfma_f32_16x16x32_bf16(
                        qa[mi][kh], sb[ni][kh], acc[mi][ni], 0, 0, 0);
        __builtin_amdgcn_s_setprio(0);
    }
    // acc += P @ v
    {
        const u16* vt = VbT + (size_t)bh * 64 * 2048;
#pragma unroll
        for (int sh = 0; sh < 2; ++sh) {
            bf16x8 pa[4], vb[4];
#pragma unroll
            for (int mi = 0; mi < 4; ++mi)
                pa[mi] = *reinterpret_cast<const bf16x8*>(
                    &P[(mi * 16 + fr) * 72 + sh * 32 + fk]);
#pragma unroll
            for (int ni = 0; ni < 4; ++ni)
                vb[ni] = *reinterpret_cast<const bf16x8*>(
                    &vt[(size_t)(ni * 16 + fr) * 2048 + c * 64 + sh * 32 + fk]);
            __builtin_amdgcn_s_setprio(1);
#pragma unroll
            for (int mi = 0; mi < 4; ++mi)
#pragma unroll
                for (int ni = 0; ni < 4; ++ni)
                    acc[mi][ni] = __builtin_amdgcn_mfma_f32_16x16x32_bf16(
                        pa[mi], vb[ni], acc[mi][ni], 0, 0, 0);
            __builtin_amdgcn_s_setprio(0);
        }
    }
    // write token-major bf16 O
#pragma unroll
    for (int mi = 0; mi < 4; ++mi)
#pragma unroll
        for (int ni = 0; ni < 4; ++ni)
#pragma unroll
            for (int r = 0; r < 4; ++r) {
                int t = tok0 + mi * 16 + fq * 4 + r;
                int n = h * 64 + ni * 16 + fr;
                Ob[(size_t)t * 1024 + n] = f2b(acc[mi][ni][r]);
            }
}

extern "C" void kernel_launch(void* const* d_in, const int* in_sizes, int n_in,
                              void* d_out, int out_size, void* d_ws, size_t ws_size,
                              hipStream_t stream)
{
    (void)in_sizes; (void)n_in; (void)out_size; (void)ws_size;
    const float* x  = (const float*)d_in[0];
    const float* Wq = (const float*)d_in[1];
    const float* bq = (const float*)d_in[2];
    const float* Wk = (const float*)d_in[3];
    const float* bk = (const float*)d_in[4];
    const float* Wv = (const float*)d_in[5];
    const float* bv = (const float*)d_in[6];
    const float* Wo = (const float*)d_in[7];
    const float* bo = (const float*)d_in[8];
    float* out = (float*)d_out;

    char* ws = (char*)d_ws;
    constexpr size_t SZ_ME = (size_t)Mq * Eq * 2;        // 8 MB
    u16*   Qb  = (u16*)  (ws + 0 * SZ_ME);
    u16*   Kb  = (u16*)  (ws + 1 * SZ_ME);
    u16*   KbT = (u16*)  (ws + 2 * SZ_ME);
    u16*   VbT = (u16*)  (ws + 3 * SZ_ME);
    u16*   Ob  = (u16*)  (ws + 4 * SZ_ME);
    u16*   KVT = (u16*)  (ws + 5 * SZ_ME);               // 8 MB bf16
    u16*   STb = (u16*)  (ws + 6 * SZ_ME);
    u16*   Xb  = (u16*)  (ws + 7 * SZ_ME);
    u16*   Wb0 = (u16*)  (ws + 8 * SZ_ME);               // [Wq|Wk|Wv|Wo] bf16
    u16* Wqkvb = Wb0;
    u16* Wob   = Wb0 + (size_t)3 * Eq * Eq;

    // 1) all bf16 conversions, one launch
    cvt_all_kernel<<<dim3(8192), dim3(256), 0, stream>>>(x, Wq, Wk, Wv, Wo, Xb, Wb0);

    // 2) fused QKV projection (M=4096, N=3072): ring GEMM, 768 blocks x 512 thr
    qkv_ring<<<dim3(768), dim3(512), 0, stream>>>(
        Xb, Wqkvb, bq, bk, bv, Qb, Kb, KbT, VbT);

    // 3) attention
    chunk_kv_kernel<<<dim3(BH * NC), dim3(64), 0, stream>>>(KbT, VbT, KVT);
    scan_kernel<<<dim3(BH * 16), dim3(256), 0, stream>>>(KVT, STb);
    attn_kernel<<<dim3(BH * NC), dim3(64), 0, stream>>>(Qb, Kb, VbT, STb, Ob);

    // 4) output projection (M=4096, N=1024): ring GEMM, 512 blocks (2/CU)
    oproj_kernel<<<dim3(512), dim3(256), 0, stream>>>(Ob, Wob, bo, out);
}